// Round 15
// baseline (64.644 us; speedup 1.0000x reference)
//
#include <hip/hip_runtime.h>
#include <hip/hip_bf16.h>

#define BB 4
#define LL 1024
#define DIMD 512
#define HH 8
#define EHD 64
#define NBUCK 1023

using f32x4 = __attribute__((ext_vector_type(4))) float;
using s16x8 = __attribute__((ext_vector_type(8))) short;

__device__ __forceinline__ ushort to_bf16(float x) {
    union { float f; unsigned u; } v; v.f = x;
    unsigned r = (v.u + 0x7FFFu + ((v.u >> 16) & 1u)) >> 16;
    return (ushort)r;
}

__device__ __forceinline__ unsigned cvt_pk_bf16(float lo, float hi) {
    unsigned r;
    asm("v_cvt_pk_bf16_f32 %0, %1, %2" : "=v"(r) : "v"(lo), "v"(hi));
    return r;
}

__device__ __forceinline__ void gl_lds16(const ushort* g, ushort* l) {
    __builtin_amdgcn_global_load_lds(
        (const __attribute__((address_space(1))) unsigned int*)g,
        (__attribute__((address_space(3))) unsigned int*)l, 16, 0, 0);
}

// ---------------------------------------------------------------------------
// Fused prep: bf16 conversion of x/W_in/W_out + RoPE cos/sin table.
// ---------------------------------------------------------------------------
#define XN  2097152
#define WIN 786432
#define WON 262144
__global__ __launch_bounds__(256) void prep_all(const float* __restrict__ x,
                                                const float* __restrict__ wi,
                                                const float* __restrict__ wo,
                                                ushort* __restrict__ xb,
                                                ushort* __restrict__ wib,
                                                ushort* __restrict__ wob,
                                                float2* __restrict__ rtab)
{
    if (blockIdx.x < 3072) {
        int idx = (blockIdx.x * 256 + threadIdx.x) * 4;
        const float* src; ushort* dst; int off;
        if (idx < XN)            { src = x;  dst = xb;  off = idx; }
        else if (idx < XN + WIN) { src = wi; dst = wib; off = idx - XN; }
        else                     { src = wo; dst = wob; off = idx - XN - WIN; }
        float4 v = *(const float4*)&src[off];
        ushort4 o;
        o.x = to_bf16(v.x); o.y = to_bf16(v.y);
        o.z = to_bf16(v.z); o.w = to_bf16(v.w);
        *(ushort4*)&dst[off] = o;
    } else {
        int idx = (blockIdx.x - 3072) * 256 + threadIdx.x;   // 16384
        int tt = idx >> 5, e = idx & 31;
        const float L2T = 13.287712379549449f;               // log2(10000)
        float inv = exp2f(-(float)e * (L2T / 32.f));
        float ang = (float)tt * inv;
        float s, c;
        sincosf(ang, &s, &c);
        rtab[idx] = make_float2(c, s);
    }
}

// ---------------------------------------------------------------------------
// MFMA GEMM, 2-phase double-buffered staging with COUNTED vmcnt (T4):
// STAGE(next); vmcnt(N); barrier; compute; barrier — loads never drained to 0
// in the loop body. WMODE 1 epilogue: rope via table lookup.
// ---------------------------------------------------------------------------
template<int BN, int WMODE>
__global__ __launch_bounds__(256) void mfma_gemm(const ushort* __restrict__ A,
                                                 const ushort* __restrict__ B,
                                                 const float* __restrict__ bias,
                                                 float* __restrict__ outf,
                                                 ushort* __restrict__ outq,
                                                 ushort* __restrict__ outk,
                                                 ushort* __restrict__ outv,
                                                 const int* __restrict__ time_ids,
                                                 const float2* __restrict__ rtab,
                                                 int M, int N, int K)
{
    constexpr int NREP = BN / 32;
    constexpr int BUFU = 8192 + BN * 64;            // ushorts per buffer
    __shared__ __align__(16) char smem[2 * BUFU * 2];
    ushort* base = (ushort*)smem;

    const int t = threadIdx.x;
    const int lane = t & 63;
    const int w = t >> 6;
    const int l15 = lane & 15, lg = lane >> 4;
    const int wr = w >> 1, wc = w & 1;
    const int m0 = blockIdx.x * 128;
    const int n0 = blockIdx.y * BN;

    const int asub = lane >> 3;
    const int kc8 = (lane & 7) * 8;
    const int arow_base = w * 32;
    const int brow_base = w * (BN / 4);

    f32x4 acc[4][NREP];
    #pragma unroll
    for (int mf = 0; mf < 4; ++mf)
        #pragma unroll
        for (int nf = 0; nf < NREP; ++nf)
            acc[mf][nf] = {0.f, 0.f, 0.f, 0.f};

    #define STAGE_G(BUF, K0)                                                          \
        do {                                                                          \
            ushort* Ab = base + (BUF) * BUFU;                                         \
            ushort* Bb = Ab + 8192;                                                   \
            _Pragma("unroll")                                                         \
            for (int i = 0; i < 4; ++i) {                                             \
                int row = arow_base + i * 8;                                          \
                gl_lds16(&A[(size_t)(m0 + row + asub) * K + (K0) + kc8], &Ab[row * 64]); \
            }                                                                         \
            _Pragma("unroll")                                                         \
            for (int i = 0; i < BN / 32; ++i) {                                       \
                int row = brow_base + i * 8;                                          \
                gl_lds16(&B[(size_t)(n0 + row + asub) * K + (K0) + kc8], &Bb[row * 64]); \
            }                                                                         \
        } while (0)

    STAGE_G(0, 0);
    __syncthreads();   // prologue: tile 0 published (full drain, once)

    for (int k0 = 0; k0 < K; k0 += 64) {
        const int buf = (k0 >> 6) & 1;
        if (k0 + 64 < K) {
            STAGE_G(buf ^ 1, k0 + 64);
            if constexpr (BN == 128) asm volatile("s_waitcnt vmcnt(8)" ::: "memory");
            else                     asm volatile("s_waitcnt vmcnt(6)" ::: "memory");
        } else {
            asm volatile("s_waitcnt vmcnt(0)" ::: "memory");
        }
        __builtin_amdgcn_s_barrier();       // tile k0 published for all waves
        ushort* Abuf = base + buf * BUFU;
        ushort* Bbuf = Abuf + 8192;
        #pragma unroll
        for (int kk = 0; kk < 2; ++kk) {
            s16x8 af[4], bf[NREP];
            #pragma unroll
            for (int mf = 0; mf < 4; ++mf)
                af[mf] = *(const s16x8*)&Abuf[(wr * 64 + mf * 16 + l15) * 64 + kk * 32 + lg * 8];
            #pragma unroll
            for (int nf = 0; nf < NREP; ++nf)
                bf[nf] = *(const s16x8*)&Bbuf[(wc * (BN / 2) + nf * 16 + l15) * 64 + kk * 32 + lg * 8];
            __builtin_amdgcn_s_setprio(1);
            #pragma unroll
            for (int mf = 0; mf < 4; ++mf)
                #pragma unroll
                for (int nf = 0; nf < NREP; ++nf)
                    acc[mf][nf] = __builtin_amdgcn_mfma_f32_16x16x32_bf16(af[mf], bf[nf], acc[mf][nf], 0, 0, 0);
            __builtin_amdgcn_s_setprio(0);
        }
        asm volatile("" ::: "memory");
        __builtin_amdgcn_s_barrier();       // reads done -> next STAGE may overwrite
    }

    if (WMODE == 0) {
        float bv[NREP];
        #pragma unroll
        for (int nf = 0; nf < NREP; ++nf) bv[nf] = bias[n0 + wc * (BN / 2) + nf * 16 + l15];
        #pragma unroll
        for (int mf = 0; mf < 4; ++mf)
            #pragma unroll
            for (int r = 0; r < 4; ++r) {
                int m = m0 + wr * 64 + mf * 16 + lg * 4 + r;
                #pragma unroll
                for (int nf = 0; nf < NREP; ++nf)
                    outf[(size_t)m * N + n0 + wc * (BN / 2) + nf * 16 + l15] = acc[mf][nf][r] + bv[nf];
            }
    } else {
        const int which = n0 >> 9;
        if (which < 2) {
            const int h = ((n0 & 511) + wc * 64) >> 6;
            ushort* dst = (which == 0) ? outq : outk;
            float bv[4];
            #pragma unroll
            for (int nf = 0; nf < 4; ++nf) bv[nf] = bias[n0 + wc * 64 + nf * 16 + l15];
            #pragma unroll
            for (int mf = 0; mf < 4; ++mf)
                #pragma unroll
                for (int r = 0; r < 4; ++r) {
                    int m = m0 + wr * 64 + mf * 16 + lg * 4 + r;
                    int b = m >> 10, li = m & (LL - 1);
                    int tt = time_ids[b * LL + li];
                    size_t rowbase = (((size_t)(b * HH + h)) * LL + li) * EHD;
                    #pragma unroll
                    for (int nf = 0; nf < 2; ++nf) {
                        float2 cs = rtab[tt * 32 + nf * 16 + l15];
                        float v1 = acc[mf][nf][r] + bv[nf];
                        float v2 = acc[mf][nf + 2][r] + bv[nf + 2];
                        dst[rowbase + nf * 16 + l15]      = to_bf16(v1 * cs.x - v2 * cs.y);
                        dst[rowbase + 32 + nf * 16 + l15] = to_bf16(v2 * cs.x + v1 * cs.y);
                    }
                }
        } else {
            ushort* T = (ushort*)smem;   // [128][136]
            float bv[4];
            #pragma unroll
            for (int nf = 0; nf < 4; ++nf) bv[nf] = bias[n0 + wc * 64 + nf * 16 + l15];
            #pragma unroll
            for (int mf = 0; mf < 4; ++mf)
                #pragma unroll
                for (int nf = 0; nf < 4; ++nf) {
                    int n = wc * 64 + nf * 16 + l15;
                    int mb = wr * 64 + mf * 16 + lg * 4;
                    ushort4 pk;
                    pk.x = to_bf16(acc[mf][nf][0] + bv[nf]);
                    pk.y = to_bf16(acc[mf][nf][1] + bv[nf]);
                    pk.z = to_bf16(acc[mf][nf][2] + bv[nf]);
                    pk.w = to_bf16(acc[mf][nf][3] + bv[nf]);
                    *(ushort4*)&T[n * 136 + mb] = pk;
                }
            __syncthreads();
            const int b = m0 >> 10, li0 = m0 & (LL - 1);
            const int hbase = (n0 & 511) >> 6;
            #pragma unroll
            for (int it = 0; it < 8; ++it) {
                int n = it * 16 + (t >> 4);
                int mc = (t & 15) * 8;
                uint4 val = *(const uint4*)&T[n * 136 + mc];
                int h = hbase + (n >> 6);
                int e = n & 63;
                *(uint4*)&outv[(((size_t)(b * HH + h)) * EHD + e) * LL + li0 + mc] = val;
            }
        }
    }
}

// ---------------------------------------------------------------------------
// MFMA attention, split-K (2 halves x 4 waves), swapped QK^T, in-loop PB,
// static-max softmax, deferred d reduce, XCD-aware flat grid. COUNTED vmcnt
// staging (T4): STAGE(next); vmcnt(4); barrier; compute; barrier.
// ---------------------------------------------------------------------------
__global__ __launch_bounds__(512, 4) void attn_mfma(const ushort* __restrict__ qb,
                                                    const ushort* __restrict__ kb,
                                                    const ushort* __restrict__ vt,
                                                    const int* __restrict__ time_ids,
                                                    const float* __restrict__ rel_table,
                                                    const float* __restrict__ post_table,
                                                    ushort* __restrict__ ao)
{
    __shared__ __align__(16) char smem[65536];        // K/V staging, then merge
    __shared__ __align__(16) float rt_s[1024];        // rel*log2e - M0
    __shared__ __align__(16) float pt_s[1024];        // post, raw
    __shared__ __align__(16) int   tid4_s[1024];      // time value * 4

    const int t = threadIdx.x;                        // 0..511
    const int lane = t & 63;
    const int w = t >> 6;
    const int wh = w & 3;
    const int half = w >> 2;
    const int l15 = lane & 15, lg = lane >> 4;

    // XCD-aware block mapping (8 XCDs)
    const int wg = blockIdx.x;                        // 0..511
    const int xcd = wg & 7;
    const int j = wg >> 3;                            // 0..63
    const int bh = xcd * 4 + (j & 3);
    const int qt = j >> 2;                            // 0..15
    const int b = bh >> 3, h = bh & 7;
    const int wq0 = qt * 64 + wh * 16;

    ushort* Kh = (ushort*)smem + half * 8192;
    ushort* Vh = (ushort*)(smem + 32768) + half * 8192;

    const float L2E = 1.4426950408889634f;
    const float M0 = 12.0f;                           // static softmax shift
    for (int i = t; i < NBUCK; i += 512) {
        rt_s[i] = rel_table[h * NBUCK + i] * L2E - M0;
        pt_s[i] = post_table[h * NBUCK + i];
    }
    const int* tid_b = time_ids + b * LL;
    #pragma unroll
    for (int i = 0; i < 2; ++i) tid4_s[i * 512 + t] = tid_b[i * 512 + t] * 4;

    const ushort* qpan = qb + (size_t)bh * LL * EHD;
    const ushort* kpan = kb + (size_t)bh * LL * EHD;
    const ushort* vpan = vt + (size_t)bh * EHD * LL;

    s16x8 qf[2];
    #pragma unroll
    for (int ec = 0; ec < 2; ++ec)
        qf[ec] = *(const s16x8*)&qpan[(size_t)(wq0 + l15) * EHD + ec * 32 + lg * 8];

    const int tqA4 = (tid_b[wq0 + l15] + 511) * 4;

    const int srow = lane >> 3;
    const int sswz = (lane & 7) ^ srow;

    #define STAGE(BUF, K0)                                                        \
        do {                                                                      \
            int r0 = wh * 8 + srow;                                               \
            gl_lds16(&kpan[(size_t)((K0) + r0) * EHD + sswz * 8],      &Kh[(BUF) * 4096 + wh * 8 * 64]);        \
            gl_lds16(&vpan[(size_t)r0 * LL + (K0) + sswz * 8],         &Vh[(BUF) * 4096 + wh * 8 * 64]);        \
            gl_lds16(&kpan[(size_t)((K0) + r0 + 32) * EHD + sswz * 8], &Kh[(BUF) * 4096 + (32 + wh * 8) * 64]); \
            gl_lds16(&vpan[(size_t)(r0 + 32) * LL + (K0) + sswz * 8],  &Vh[(BUF) * 4096 + (32 + wh * 8) * 64]); \
        } while (0)

    float dreg = 0.f;
    f32x4 ot[4], o2[4];
    #pragma unroll
    for (int ei = 0; ei < 4; ++ei) {
        ot[ei] = {0.f, 0.f, 0.f, 0.f};
        o2[ei] = {0.f, 0.f, 0.f, 0.f};
    }

    const int ktbase = half * 8;
    STAGE(0, ktbase * 64);
    __syncthreads();   // prologue: tables + tile 0 published (full drain, once)

    const int srcA = ((lg & 1) << 5) + l15;
    const bool hi = (lg & 2) != 0;

    for (int i = 0; i < 8; ++i) {
        const int cur = i & 1;
        const int k0 = (ktbase + i) * 64;
        if (i < 7) {
            STAGE(cur ^ 1, k0 + 64);
            asm volatile("s_waitcnt vmcnt(4)" ::: "memory");   // my tile-i loads landed
        } else {
            asm volatile("s_waitcnt vmcnt(0)" ::: "memory");
        }
        __builtin_amdgcn_s_barrier();    // tile i published for all waves

        const char* Kc = (const char*)&Kh[cur * 4096];
        const char* Vc = (const char*)&Vh[cur * 4096];

        // ---- QK^T swapped: D[row=k][col=q], lane q = l15 ----
        f32x4 sc[4];
        #pragma unroll
        for (int ci = 0; ci < 4; ++ci) sc[ci] = {0.f, 0.f, 0.f, 0.f};
        __builtin_amdgcn_s_setprio(1);
        #pragma unroll
        for (int ec = 0; ec < 2; ++ec)
            #pragma unroll
            for (int ci = 0; ci < 4; ++ci) {
                int row = ci * 16 + l15;
                s16x8 kf = *(const s16x8*)(Kc + row * 128 +
                                           ((ec * 64 + lg * 16) ^ ((row & 7) << 4)));
                sc[ci] = __builtin_amdgcn_mfma_f32_16x16x32_bf16(kf, qf[ec], sc[ci], 0, 0, 0);
            }
        __builtin_amdgcn_s_setprio(0);

        // ---- V fragments ----
        s16x8 vf[4][2];
        #pragma unroll
        for (int ei = 0; ei < 4; ++ei)
            #pragma unroll
            for (int kk = 0; kk < 2; ++kk) {
                int row = ei * 16 + l15;
                vf[ei][kk] = *(const s16x8*)(Vc + row * 128 +
                                             ((kk * 64 + lg * 16) ^ ((row & 7) << 4)));
            }

        // ---- PB pass: B-frag straight from tables ----
        #pragma unroll
        for (int kk = 0; kk < 2; ++kk) {
            int4 ta = *(const int4*)&tid4_s[k0 + kk * 32 + lg * 8];
            int4 tb = *(const int4*)&tid4_s[k0 + kk * 32 + lg * 8 + 4];
            float p0 = *(const float*)((const char*)pt_s + (tqA4 - ta.x));
            float p1 = *(const float*)((const char*)pt_s + (tqA4 - ta.y));
            float p2 = *(const float*)((const char*)pt_s + (tqA4 - ta.z));
            float p3 = *(const float*)((const char*)pt_s + (tqA4 - ta.w));
            float p4 = *(const float*)((const char*)pt_s + (tqA4 - tb.x));
            float p5 = *(const float*)((const char*)pt_s + (tqA4 - tb.y));
            float p6 = *(const float*)((const char*)pt_s + (tqA4 - tb.z));
            float p7 = *(const float*)((const char*)pt_s + (tqA4 - tb.w));
            union { unsigned u[4]; s16x8 v; } pbu;
            pbu.u[0] = cvt_pk_bf16(p0, p1);
            pbu.u[1] = cvt_pk_bf16(p2, p3);
            pbu.u[2] = cvt_pk_bf16(p4, p5);
            pbu.u[3] = cvt_pk_bf16(p6, p7);
            __builtin_amdgcn_s_setprio(1);
            #pragma unroll
            for (int ei = 0; ei < 4; ++ei)
                o2[ei] = __builtin_amdgcn_mfma_f32_16x16x32_bf16(vf[ei][kk], pbu.v, o2[ei], 0, 0, 0);
            __builtin_amdgcn_s_setprio(0);
        }

        // ---- static-max softmax: p = exp2(sc*scale + (rel*L2E - M0)) ----
        float rsum = 0.f;
        #pragma unroll
        for (int ci = 0; ci < 4; ++ci) {
            int4 tk4 = *(const int4*)&tid4_s[k0 + ci * 16 + lg * 4];
            float p0 = exp2f(sc[ci][0] * 0.18033688011111793f + *(const float*)((const char*)rt_s + (tqA4 - tk4.x)));
            float p1 = exp2f(sc[ci][1] * 0.18033688011111793f + *(const float*)((const char*)rt_s + (tqA4 - tk4.y)));
            float p2 = exp2f(sc[ci][2] * 0.18033688011111793f + *(const float*)((const char*)rt_s + (tqA4 - tk4.z)));
            float p3 = exp2f(sc[ci][3] * 0.18033688011111793f + *(const float*)((const char*)rt_s + (tqA4 - tk4.w)));
            sc[ci][0] = p0; sc[ci][1] = p1; sc[ci][2] = p2; sc[ci][3] = p3;
            rsum += (p0 + p1) + (p2 + p3);
        }
        dreg += rsum;

        // ---- pack P to bf16 pairs ----
        unsigned pk[4][2];
        #pragma unroll
        for (int ci = 0; ci < 4; ++ci) {
            pk[ci][0] = cvt_pk_bf16(sc[ci][0], sc[ci][1]);
            pk[ci][1] = cvt_pk_bf16(sc[ci][2], sc[ci][3]);
        }

        // ---- exchange to PV B-frag layout + PV ----
        #pragma unroll
        for (int kk = 0; kk < 2; ++kk) {
            unsigned a0 = __shfl(pk[kk * 2][0], srcA),      b0 = __shfl(pk[kk * 2 + 1][0], srcA);
            unsigned a1 = __shfl(pk[kk * 2][1], srcA),      b1 = __shfl(pk[kk * 2 + 1][1], srcA);
            unsigned a2 = __shfl(pk[kk * 2][0], srcA + 16), b2 = __shfl(pk[kk * 2 + 1][0], srcA + 16);
            unsigned a3 = __shfl(pk[kk * 2][1], srcA + 16), b3 = __shfl(pk[kk * 2 + 1][1], srcA + 16);
            union { unsigned u[4]; s16x8 v; } pb;
            pb.u[0] = hi ? b0 : a0;
            pb.u[1] = hi ? b1 : a1;
            pb.u[2] = hi ? b2 : a2;
            pb.u[3] = hi ? b3 : a3;
            __builtin_amdgcn_s_setprio(1);
            #pragma unroll
            for (int ei = 0; ei < 4; ++ei)
                ot[ei] = __builtin_amdgcn_mfma_f32_16x16x32_bf16(vf[ei][kk], pb.v, ot[ei], 0, 0, 0);
            __builtin_amdgcn_s_setprio(0);
        }

        asm volatile("" ::: "memory");
        __builtin_amdgcn_s_barrier();    // reads done -> next STAGE may overwrite
    }

    // ---- deferred d reduce (once) ----
    dreg += __shfl_xor(dreg, 16);
    dreg += __shfl_xor(dreg, 32);

    // ---- split-K merge through LDS (staging region dead) ----
    float* mergeO = (float*)smem;                  // [64][68] f32
    float* mergeB = (float*)(smem + 17408);        // [64][68] f32
    float* mergeD = (float*)(smem + 34816);        // [64]     f32
    const int mrow = wh * 16 + l15;

    if (half == 1) {
        #pragma unroll
        for (int ei = 0; ei < 4; ++ei) {
            *(float4*)&mergeO[mrow * 68 + ei * 16 + lg * 4] =
                make_float4(ot[ei][0], ot[ei][1], ot[ei][2], ot[ei][3]);
            *(float4*)&mergeB[mrow * 68 + ei * 16 + lg * 4] =
                make_float4(o2[ei][0], o2[ei][1], o2[ei][2], o2[ei][3]);
        }
        if (lg == 0) mergeD[mrow] = dreg;
    }
    __syncthreads();

    if (half == 0) {
        float invd = 1.f / (dreg + mergeD[mrow]);
        const size_t orow = (size_t)(b * LL + wq0 + l15) * DIMD + h * EHD;
        #pragma unroll
        for (int ei = 0; ei < 4; ++ei) {
            float4 o1 = *(const float4*)&mergeO[mrow * 68 + ei * 16 + lg * 4];
            float4 b1 = *(const float4*)&mergeB[mrow * 68 + ei * 16 + lg * 4];
            ushort4 st;
            st.x = to_bf16((ot[ei][0] + o1.x) * invd + o2[ei][0] + b1.x);
            st.y = to_bf16((ot[ei][1] + o1.y) * invd + o2[ei][1] + b1.y);
            st.z = to_bf16((ot[ei][2] + o1.z) * invd + o2[ei][2] + b1.z);
            st.w = to_bf16((ot[ei][3] + o1.w) * invd + o2[ei][3] + b1.w);
            *(ushort4*)&ao[orow + ei * 16 + lg * 4] = st;
        }
    }
}

extern "C" void kernel_launch(void* const* d_in, const int* in_sizes, int n_in,
                              void* d_out, int out_size, void* d_ws, size_t ws_size,
                              hipStream_t stream)
{
    const float* x        = (const float*)d_in[0];
    const int*   time_ids = (const int*)d_in[2];
    const float* W_in     = (const float*)d_in[3];
    const float* b_in     = (const float*)d_in[4];
    const float* W_out    = (const float*)d_in[5];
    const float* b_out    = (const float*)d_in[6];
    const float* rel_t    = (const float*)d_in[7];
    const float* post_t   = (const float*)d_in[8];
    float* out = (float*)d_out;

    ushort* wsu = (ushort*)d_ws;
    ushort* xb  = wsu;
    ushort* wib = xb + XN;
    ushort* wob = wib + WIN;
    ushort* qbf = wob + WON;
    ushort* kbf = qbf + XN;
    ushort* vtb = kbf + XN;
    ushort* aob = vtb + XN;
    float2* rtab = (float2*)(aob + XN);           // 16384 float2

    prep_all<<<3136, 256, 0, stream>>>(x, W_in, W_out, xb, wib, wob, rtab);
    mfma_gemm<128, 1><<<dim3(32, 12), 256, 0, stream>>>(xb, wib, b_in,
                                                        nullptr, qbf, kbf, vtb,
                                                        time_ids, (const float2*)rtab,
                                                        BB * LL, 3 * DIMD, DIMD);
    attn_mfma<<<512, 512, 0, stream>>>(qbf, kbf, vtb, time_ids,
                                       rel_t, post_t, aob);
    mfma_gemm<64, 0><<<dim3(32, 8), 256, 0, stream>>>(aob, wob, b_out,
                                                      out, nullptr, nullptr, nullptr,
                                                      nullptr, nullptr,
                                                      BB * LL, DIMD, DIMD);
}

// Round 16
// 63.843 us; speedup vs baseline: 1.0125x; 1.0125x over previous
//
#include <hip/hip_runtime.h>
#include <hip/hip_bf16.h>

#define BB 4
#define LL 1024
#define DIMD 512
#define HH 8
#define EHD 64
#define NBUCK 1023

using f32x4 = __attribute__((ext_vector_type(4))) float;
using s16x8 = __attribute__((ext_vector_type(8))) short;

__device__ __forceinline__ ushort to_bf16(float x) {
    union { float f; unsigned u; } v; v.f = x;
    unsigned r = (v.u + 0x7FFFu + ((v.u >> 16) & 1u)) >> 16;
    return (ushort)r;
}

__device__ __forceinline__ unsigned cvt_pk_bf16(float lo, float hi) {
    unsigned r;
    asm("v_cvt_pk_bf16_f32 %0, %1, %2" : "=v"(r) : "v"(lo), "v"(hi));
    return r;
}

__device__ __forceinline__ void gl_lds16(const ushort* g, ushort* l) {
    __builtin_amdgcn_global_load_lds(
        (const __attribute__((address_space(1))) unsigned int*)g,
        (__attribute__((address_space(3))) unsigned int*)l, 16, 0, 0);
}

// ---------------------------------------------------------------------------
// Fused prep: bf16 conversion of x/W_in/W_out + RoPE cos/sin table.
// ---------------------------------------------------------------------------
#define XN  2097152
#define WIN 786432
#define WON 262144
__global__ __launch_bounds__(256) void prep_all(const float* __restrict__ x,
                                                const float* __restrict__ wi,
                                                const float* __restrict__ wo,
                                                ushort* __restrict__ xb,
                                                ushort* __restrict__ wib,
                                                ushort* __restrict__ wob,
                                                float2* __restrict__ rtab)
{
    if (blockIdx.x < 3072) {
        int idx = (blockIdx.x * 256 + threadIdx.x) * 4;
        const float* src; ushort* dst; int off;
        if (idx < XN)            { src = x;  dst = xb;  off = idx; }
        else if (idx < XN + WIN) { src = wi; dst = wib; off = idx - XN; }
        else                     { src = wo; dst = wob; off = idx - XN - WIN; }
        float4 v = *(const float4*)&src[off];
        ushort4 o;
        o.x = to_bf16(v.x); o.y = to_bf16(v.y);
        o.z = to_bf16(v.z); o.w = to_bf16(v.w);
        *(ushort4*)&dst[off] = o;
    } else {
        int idx = (blockIdx.x - 3072) * 256 + threadIdx.x;   // 16384
        int tt = idx >> 5, e = idx & 31;
        const float L2T = 13.287712379549449f;               // log2(10000)
        float inv = exp2f(-(float)e * (L2T / 32.f));
        float ang = (float)tt * inv;
        float s, c;
        sincosf(ang, &s, &c);
        rtab[idx] = make_float2(c, s);
    }
}

// ---------------------------------------------------------------------------
// MFMA GEMM, 2-phase double-buffered staging with counted vmcnt (unchanged
// from round 15). WMODE 1 epilogue: rope via table lookup.
// ---------------------------------------------------------------------------
template<int BN, int WMODE>
__global__ __launch_bounds__(256) void mfma_gemm(const ushort* __restrict__ A,
                                                 const ushort* __restrict__ B,
                                                 const float* __restrict__ bias,
                                                 float* __restrict__ outf,
                                                 ushort* __restrict__ outq,
                                                 ushort* __restrict__ outk,
                                                 ushort* __restrict__ outv,
                                                 const int* __restrict__ time_ids,
                                                 const float2* __restrict__ rtab,
                                                 int M, int N, int K)
{
    constexpr int NREP = BN / 32;
    constexpr int BUFU = 8192 + BN * 64;            // ushorts per buffer
    __shared__ __align__(16) char smem[2 * BUFU * 2];
    ushort* base = (ushort*)smem;

    const int t = threadIdx.x;
    const int lane = t & 63;
    const int w = t >> 6;
    const int l15 = lane & 15, lg = lane >> 4;
    const int wr = w >> 1, wc = w & 1;
    const int m0 = blockIdx.x * 128;
    const int n0 = blockIdx.y * BN;

    const int asub = lane >> 3;
    const int kc8 = (lane & 7) * 8;
    const int arow_base = w * 32;
    const int brow_base = w * (BN / 4);

    f32x4 acc[4][NREP];
    #pragma unroll
    for (int mf = 0; mf < 4; ++mf)
        #pragma unroll
        for (int nf = 0; nf < NREP; ++nf)
            acc[mf][nf] = {0.f, 0.f, 0.f, 0.f};

    #define STAGE_G(BUF, K0)                                                          \
        do {                                                                          \
            ushort* Ab = base + (BUF) * BUFU;                                         \
            ushort* Bb = Ab + 8192;                                                   \
            _Pragma("unroll")                                                         \
            for (int i = 0; i < 4; ++i) {                                             \
                int row = arow_base + i * 8;                                          \
                gl_lds16(&A[(size_t)(m0 + row + asub) * K + (K0) + kc8], &Ab[row * 64]); \
            }                                                                         \
            _Pragma("unroll")                                                         \
            for (int i = 0; i < BN / 32; ++i) {                                       \
                int row = brow_base + i * 8;                                          \
                gl_lds16(&B[(size_t)(n0 + row + asub) * K + (K0) + kc8], &Bb[row * 64]); \
            }                                                                         \
        } while (0)

    STAGE_G(0, 0);
    __syncthreads();   // prologue: tile 0 published (full drain, once)

    for (int k0 = 0; k0 < K; k0 += 64) {
        const int buf = (k0 >> 6) & 1;
        if (k0 + 64 < K) {
            STAGE_G(buf ^ 1, k0 + 64);
            if constexpr (BN == 128) asm volatile("s_waitcnt vmcnt(8)" ::: "memory");
            else                     asm volatile("s_waitcnt vmcnt(6)" ::: "memory");
        } else {
            asm volatile("s_waitcnt vmcnt(0)" ::: "memory");
        }
        __builtin_amdgcn_s_barrier();
        ushort* Abuf = base + buf * BUFU;
        ushort* Bbuf = Abuf + 8192;
        #pragma unroll
        for (int kk = 0; kk < 2; ++kk) {
            s16x8 af[4], bf[NREP];
            #pragma unroll
            for (int mf = 0; mf < 4; ++mf)
                af[mf] = *(const s16x8*)&Abuf[(wr * 64 + mf * 16 + l15) * 64 + kk * 32 + lg * 8];
            #pragma unroll
            for (int nf = 0; nf < NREP; ++nf)
                bf[nf] = *(const s16x8*)&Bbuf[(wc * (BN / 2) + nf * 16 + l15) * 64 + kk * 32 + lg * 8];
            __builtin_amdgcn_s_setprio(1);
            #pragma unroll
            for (int mf = 0; mf < 4; ++mf)
                #pragma unroll
                for (int nf = 0; nf < NREP; ++nf)
                    acc[mf][nf] = __builtin_amdgcn_mfma_f32_16x16x32_bf16(af[mf], bf[nf], acc[mf][nf], 0, 0, 0);
            __builtin_amdgcn_s_setprio(0);
        }
        asm volatile("" ::: "memory");
        __builtin_amdgcn_s_barrier();
    }

    if (WMODE == 0) {
        float bv[NREP];
        #pragma unroll
        for (int nf = 0; nf < NREP; ++nf) bv[nf] = bias[n0 + wc * (BN / 2) + nf * 16 + l15];
        #pragma unroll
        for (int mf = 0; mf < 4; ++mf)
            #pragma unroll
            for (int r = 0; r < 4; ++r) {
                int m = m0 + wr * 64 + mf * 16 + lg * 4 + r;
                #pragma unroll
                for (int nf = 0; nf < NREP; ++nf)
                    outf[(size_t)m * N + n0 + wc * (BN / 2) + nf * 16 + l15] = acc[mf][nf][r] + bv[nf];
            }
    } else {
        const int which = n0 >> 9;
        if (which < 2) {
            const int h = ((n0 & 511) + wc * 64) >> 6;
            ushort* dst = (which == 0) ? outq : outk;
            float bv[4];
            #pragma unroll
            for (int nf = 0; nf < 4; ++nf) bv[nf] = bias[n0 + wc * 64 + nf * 16 + l15];
            #pragma unroll
            for (int mf = 0; mf < 4; ++mf)
                #pragma unroll
                for (int r = 0; r < 4; ++r) {
                    int m = m0 + wr * 64 + mf * 16 + lg * 4 + r;
                    int b = m >> 10, li = m & (LL - 1);
                    int tt = time_ids[b * LL + li];
                    size_t rowbase = (((size_t)(b * HH + h)) * LL + li) * EHD;
                    #pragma unroll
                    for (int nf = 0; nf < 2; ++nf) {
                        float2 cs = rtab[tt * 32 + nf * 16 + l15];
                        float v1 = acc[mf][nf][r] + bv[nf];
                        float v2 = acc[mf][nf + 2][r] + bv[nf + 2];
                        dst[rowbase + nf * 16 + l15]      = to_bf16(v1 * cs.x - v2 * cs.y);
                        dst[rowbase + 32 + nf * 16 + l15] = to_bf16(v2 * cs.x + v1 * cs.y);
                    }
                }
        } else {
            ushort* T = (ushort*)smem;   // [128][136]
            float bv[4];
            #pragma unroll
            for (int nf = 0; nf < 4; ++nf) bv[nf] = bias[n0 + wc * 64 + nf * 16 + l15];
            #pragma unroll
            for (int mf = 0; mf < 4; ++mf)
                #pragma unroll
                for (int nf = 0; nf < 4; ++nf) {
                    int n = wc * 64 + nf * 16 + l15;
                    int mb = wr * 64 + mf * 16 + lg * 4;
                    ushort4 pk;
                    pk.x = to_bf16(acc[mf][nf][0] + bv[nf]);
                    pk.y = to_bf16(acc[mf][nf][1] + bv[nf]);
                    pk.z = to_bf16(acc[mf][nf][2] + bv[nf]);
                    pk.w = to_bf16(acc[mf][nf][3] + bv[nf]);
                    *(ushort4*)&T[n * 136 + mb] = pk;
                }
            __syncthreads();
            const int b = m0 >> 10, li0 = m0 & (LL - 1);
            const int hbase = (n0 & 511) >> 6;
            #pragma unroll
            for (int it = 0; it < 8; ++it) {
                int n = it * 16 + (t >> 4);
                int mc = (t & 15) * 8;
                uint4 val = *(const uint4*)&T[n * 136 + mc];
                int h = hbase + (n >> 6);
                int e = n & 63;
                *(uint4*)&outv[(((size_t)(b * HH + h)) * EHD + e) * LL + li0 + mc] = val;
            }
        }
    }
}

// ---------------------------------------------------------------------------
// MFMA attention v16: split-K (2 halves x 4 waves) and 2 INDEPENDENT q-groups
// per wave (32 q-rows/wave, 128 q-rows/block). K/V frags, STAGE, barriers and
// tables are shared across groups; QK/PB/PV/softmax run as two independent
// streams for in-wave ILP. Swapped QK^T, in-loop PB, static-max softmax,
// deferred d reduce, counted vmcnt, XCD-aware grid (256 blocks).
// ---------------------------------------------------------------------------
__global__ __launch_bounds__(512, 2) void attn_mfma(const ushort* __restrict__ qb,
                                                    const ushort* __restrict__ kb,
                                                    const ushort* __restrict__ vt,
                                                    const int* __restrict__ time_ids,
                                                    const float* __restrict__ rel_table,
                                                    const float* __restrict__ post_table,
                                                    ushort* __restrict__ ao)
{
    __shared__ __align__(16) char smem[65536];        // K/V staging, then merge
    __shared__ __align__(16) float rt_s[1024];        // rel*log2e - M0
    __shared__ __align__(16) float pt_s[1024];        // post, raw
    __shared__ __align__(16) int   tid4_s[1024];      // time value * 4

    const int t = threadIdx.x;                        // 0..511
    const int lane = t & 63;
    const int w = t >> 6;
    const int wh = w & 3;
    const int half = w >> 2;
    const int l15 = lane & 15, lg = lane >> 4;

    // XCD-aware block mapping (8 XCDs, 256 blocks)
    const int wg = blockIdx.x;                        // 0..255
    const int xcd = wg & 7;
    const int j = wg >> 3;                            // 0..31
    const int bh = xcd * 4 + (j & 3);
    const int qt = j >> 2;                            // 0..7
    const int b = bh >> 3, h = bh & 7;
    const int wq0 = qt * 128 + wh * 32;

    ushort* Kh = (ushort*)smem + half * 8192;
    ushort* Vh = (ushort*)(smem + 32768) + half * 8192;

    const float L2E = 1.4426950408889634f;
    const float M0 = 12.0f;                           // static softmax shift
    for (int i = t; i < NBUCK; i += 512) {
        rt_s[i] = rel_table[h * NBUCK + i] * L2E - M0;
        pt_s[i] = post_table[h * NBUCK + i];
    }
    const int* tid_b = time_ids + b * LL;
    #pragma unroll
    for (int i = 0; i < 2; ++i) tid4_s[i * 512 + t] = tid_b[i * 512 + t] * 4;

    const ushort* qpan = qb + (size_t)bh * LL * EHD;
    const ushort* kpan = kb + (size_t)bh * LL * EHD;
    const ushort* vpan = vt + (size_t)bh * EHD * LL;

    s16x8 qf[2][2];
    #pragma unroll
    for (int g = 0; g < 2; ++g)
        #pragma unroll
        for (int ec = 0; ec < 2; ++ec)
            qf[g][ec] = *(const s16x8*)&qpan[(size_t)(wq0 + g * 16 + l15) * EHD + ec * 32 + lg * 8];

    const int tqA4[2] = {(tid_b[wq0 + l15] + 511) * 4,
                         (tid_b[wq0 + 16 + l15] + 511) * 4};

    const int srow = lane >> 3;
    const int sswz = (lane & 7) ^ srow;

    #define STAGE(BUF, K0)                                                        \
        do {                                                                      \
            int r0 = wh * 8 + srow;                                               \
            gl_lds16(&kpan[(size_t)((K0) + r0) * EHD + sswz * 8],      &Kh[(BUF) * 4096 + wh * 8 * 64]);        \
            gl_lds16(&vpan[(size_t)r0 * LL + (K0) + sswz * 8],         &Vh[(BUF) * 4096 + wh * 8 * 64]);        \
            gl_lds16(&kpan[(size_t)((K0) + r0 + 32) * EHD + sswz * 8], &Kh[(BUF) * 4096 + (32 + wh * 8) * 64]); \
            gl_lds16(&vpan[(size_t)(r0 + 32) * LL + (K0) + sswz * 8],  &Vh[(BUF) * 4096 + (32 + wh * 8) * 64]); \
        } while (0)

    float dreg[2] = {0.f, 0.f};
    f32x4 ot[2][4], o2[2][4];
    #pragma unroll
    for (int g = 0; g < 2; ++g)
        #pragma unroll
        for (int ei = 0; ei < 4; ++ei) {
            ot[g][ei] = {0.f, 0.f, 0.f, 0.f};
            o2[g][ei] = {0.f, 0.f, 0.f, 0.f};
        }

    const int ktbase = half * 8;
    STAGE(0, ktbase * 64);
    __syncthreads();   // prologue: tables + tile 0 published (full drain, once)

    const int srcA = ((lg & 1) << 5) + l15;
    const bool hi = (lg & 2) != 0;

    for (int i = 0; i < 8; ++i) {
        const int cur = i & 1;
        const int k0 = (ktbase + i) * 64;
        if (i < 7) {
            STAGE(cur ^ 1, k0 + 64);
            asm volatile("s_waitcnt vmcnt(4)" ::: "memory");
        } else {
            asm volatile("s_waitcnt vmcnt(0)" ::: "memory");
        }
        __builtin_amdgcn_s_barrier();    // tile i published for all waves

        const char* Kc = (const char*)&Kh[cur * 4096];
        const char* Vc = (const char*)&Vh[cur * 4096];

        // ---- K fragments (shared by both q-groups) ----
        s16x8 kf[4][2];
        #pragma unroll
        for (int ci = 0; ci < 4; ++ci)
            #pragma unroll
            for (int ec = 0; ec < 2; ++ec) {
                int row = ci * 16 + l15;
                kf[ci][ec] = *(const s16x8*)(Kc + row * 128 +
                                             ((ec * 64 + lg * 16) ^ ((row & 7) << 4)));
            }

        // ---- QK^T swapped, both groups interleaved ----
        f32x4 sc[2][4];
        #pragma unroll
        for (int g = 0; g < 2; ++g)
            #pragma unroll
            for (int ci = 0; ci < 4; ++ci) sc[g][ci] = {0.f, 0.f, 0.f, 0.f};
        __builtin_amdgcn_s_setprio(1);
        #pragma unroll
        for (int ec = 0; ec < 2; ++ec)
            #pragma unroll
            for (int ci = 0; ci < 4; ++ci)
                #pragma unroll
                for (int g = 0; g < 2; ++g)
                    sc[g][ci] = __builtin_amdgcn_mfma_f32_16x16x32_bf16(kf[ci][ec], qf[g][ec], sc[g][ci], 0, 0, 0);
        __builtin_amdgcn_s_setprio(0);

        // ---- V fragments (shared) ----
        s16x8 vf[4][2];
        #pragma unroll
        for (int ei = 0; ei < 4; ++ei)
            #pragma unroll
            for (int kk = 0; kk < 2; ++kk) {
                int row = ei * 16 + l15;
                vf[ei][kk] = *(const s16x8*)(Vc + row * 128 +
                                             ((kk * 64 + lg * 16) ^ ((row & 7) << 4)));
            }

        // ---- PB pass, both groups (time indices shared) ----
        #pragma unroll
        for (int kk = 0; kk < 2; ++kk) {
            int4 ta = *(const int4*)&tid4_s[k0 + kk * 32 + lg * 8];
            int4 tb = *(const int4*)&tid4_s[k0 + kk * 32 + lg * 8 + 4];
            #pragma unroll
            for (int g = 0; g < 2; ++g) {
                float p0 = *(const float*)((const char*)pt_s + (tqA4[g] - ta.x));
                float p1 = *(const float*)((const char*)pt_s + (tqA4[g] - ta.y));
                float p2 = *(const float*)((const char*)pt_s + (tqA4[g] - ta.z));
                float p3 = *(const float*)((const char*)pt_s + (tqA4[g] - ta.w));
                float p4 = *(const float*)((const char*)pt_s + (tqA4[g] - tb.x));
                float p5 = *(const float*)((const char*)pt_s + (tqA4[g] - tb.y));
                float p6 = *(const float*)((const char*)pt_s + (tqA4[g] - tb.z));
                float p7 = *(const float*)((const char*)pt_s + (tqA4[g] - tb.w));
                union { unsigned u[4]; s16x8 v; } pbu;
                pbu.u[0] = cvt_pk_bf16(p0, p1);
                pbu.u[1] = cvt_pk_bf16(p2, p3);
                pbu.u[2] = cvt_pk_bf16(p4, p5);
                pbu.u[3] = cvt_pk_bf16(p6, p7);
                __builtin_amdgcn_s_setprio(1);
                #pragma unroll
                for (int ei = 0; ei < 4; ++ei)
                    o2[g][ei] = __builtin_amdgcn_mfma_f32_16x16x32_bf16(vf[ei][kk], pbu.v, o2[g][ei], 0, 0, 0);
                __builtin_amdgcn_s_setprio(0);
            }
        }

        // ---- static-max softmax, both groups (tk indices shared) ----
        float rsum[2] = {0.f, 0.f};
        #pragma unroll
        for (int ci = 0; ci < 4; ++ci) {
            int4 tk4 = *(const int4*)&tid4_s[k0 + ci * 16 + lg * 4];
            #pragma unroll
            for (int g = 0; g < 2; ++g) {
                float p0 = exp2f(sc[g][ci][0] * 0.18033688011111793f + *(const float*)((const char*)rt_s + (tqA4[g] - tk4.x)));
                float p1 = exp2f(sc[g][ci][1] * 0.18033688011111793f + *(const float*)((const char*)rt_s + (tqA4[g] - tk4.y)));
                float p2 = exp2f(sc[g][ci][2] * 0.18033688011111793f + *(const float*)((const char*)rt_s + (tqA4[g] - tk4.z)));
                float p3 = exp2f(sc[g][ci][3] * 0.18033688011111793f + *(const float*)((const char*)rt_s + (tqA4[g] - tk4.w)));
                sc[g][ci][0] = p0; sc[g][ci][1] = p1; sc[g][ci][2] = p2; sc[g][ci][3] = p3;
                rsum[g] += (p0 + p1) + (p2 + p3);
            }
        }
        dreg[0] += rsum[0];
        dreg[1] += rsum[1];

        // ---- pack P to bf16 pairs ----
        unsigned pk[2][4][2];
        #pragma unroll
        for (int g = 0; g < 2; ++g)
            #pragma unroll
            for (int ci = 0; ci < 4; ++ci) {
                pk[g][ci][0] = cvt_pk_bf16(sc[g][ci][0], sc[g][ci][1]);
                pk[g][ci][1] = cvt_pk_bf16(sc[g][ci][2], sc[g][ci][3]);
            }

        // ---- exchange to PV B-frag layout + PV, both groups ----
        #pragma unroll
        for (int g = 0; g < 2; ++g)
            #pragma unroll
            for (int kk = 0; kk < 2; ++kk) {
                unsigned a0 = __shfl(pk[g][kk * 2][0], srcA),      b0 = __shfl(pk[g][kk * 2 + 1][0], srcA);
                unsigned a1 = __shfl(pk[g][kk * 2][1], srcA),      b1 = __shfl(pk[g][kk * 2 + 1][1], srcA);
                unsigned a2 = __shfl(pk[g][kk * 2][0], srcA + 16), b2 = __shfl(pk[g][kk * 2 + 1][0], srcA + 16);
                unsigned a3 = __shfl(pk[g][kk * 2][1], srcA + 16), b3 = __shfl(pk[g][kk * 2 + 1][1], srcA + 16);
                union { unsigned u[4]; s16x8 v; } pb;
                pb.u[0] = hi ? b0 : a0;
                pb.u[1] = hi ? b1 : a1;
                pb.u[2] = hi ? b2 : a2;
                pb.u[3] = hi ? b3 : a3;
                __builtin_amdgcn_s_setprio(1);
                #pragma unroll
                for (int ei = 0; ei < 4; ++ei)
                    ot[g][ei] = __builtin_amdgcn_mfma_f32_16x16x32_bf16(vf[ei][kk], pb.v, ot[g][ei], 0, 0, 0);
                __builtin_amdgcn_s_setprio(0);
            }

        asm volatile("" ::: "memory");
        __builtin_amdgcn_s_barrier();    // reads done -> next STAGE may overwrite
    }

    // ---- deferred d reduce (once per group) ----
    #pragma unroll
    for (int g = 0; g < 2; ++g) {
        dreg[g] += __shfl_xor(dreg[g], 16);
        dreg[g] += __shfl_xor(dreg[g], 32);
    }

    // ---- split-K merge through LDS, two rounds (one per q-group) ----
    float* mergeO = (float*)smem;                  // [64][68] f32
    float* mergeB = (float*)(smem + 17408);        // [64][68] f32
    float* mergeD = (float*)(smem + 34816);        // [64]     f32
    const int mrow = wh * 16 + l15;

    #pragma unroll
    for (int g = 0; g < 2; ++g) {
        __syncthreads();   // staging dead / previous round's reads done
        if (half == 1) {
            #pragma unroll
            for (int ei = 0; ei < 4; ++ei) {
                *(float4*)&mergeO[mrow * 68 + ei * 16 + lg * 4] =
                    make_float4(ot[g][ei][0], ot[g][ei][1], ot[g][ei][2], ot[g][ei][3]);
                *(float4*)&mergeB[mrow * 68 + ei * 16 + lg * 4] =
                    make_float4(o2[g][ei][0], o2[g][ei][1], o2[g][ei][2], o2[g][ei][3]);
            }
            if (lg == 0) mergeD[mrow] = dreg[g];
        }
        __syncthreads();
        if (half == 0) {
            float invd = 1.f / (dreg[g] + mergeD[mrow]);
            const size_t orow = (size_t)(b * LL + wq0 + g * 16 + l15) * DIMD + h * EHD;
            #pragma unroll
            for (int ei = 0; ei < 4; ++ei) {
                float4 o1 = *(const float4*)&mergeO[mrow * 68 + ei * 16 + lg * 4];
                float4 b1 = *(const float4*)&mergeB[mrow * 68 + ei * 16 + lg * 4];
                ushort4 st;
                st.x = to_bf16((ot[g][ei][0] + o1.x) * invd + o2[g][ei][0] + b1.x);
                st.y = to_bf16((ot[g][ei][1] + o1.y) * invd + o2[g][ei][1] + b1.y);
                st.z = to_bf16((ot[g][ei][2] + o1.z) * invd + o2[g][ei][2] + b1.z);
                st.w = to_bf16((ot[g][ei][3] + o1.w) * invd + o2[g][ei][3] + b1.w);
                *(ushort4*)&ao[orow + ei * 16 + lg * 4] = st;
            }
        }
    }
}

extern "C" void kernel_launch(void* const* d_in, const int* in_sizes, int n_in,
                              void* d_out, int out_size, void* d_ws, size_t ws_size,
                              hipStream_t stream)
{
    const float* x        = (const float*)d_in[0];
    const int*   time_ids = (const int*)d_in[2];
    const float* W_in     = (const float*)d_in[3];
    const float* b_in     = (const float*)d_in[4];
    const float* W_out    = (const float*)d_in[5];
    const float* b_out    = (const float*)d_in[6];
    const float* rel_t    = (const float*)d_in[7];
    const float* post_t   = (const float*)d_in[8];
    float* out = (float*)d_out;

    ushort* wsu = (ushort*)d_ws;
    ushort* xb  = wsu;
    ushort* wib = xb + XN;
    ushort* wob = wib + WIN;
    ushort* qbf = wob + WON;
    ushort* kbf = qbf + XN;
    ushort* vtb = kbf + XN;
    ushort* aob = vtb + XN;
    float2* rtab = (float2*)(aob + XN);           // 16384 float2

    prep_all<<<3136, 256, 0, stream>>>(x, W_in, W_out, xb, wib, wob, rtab);
    mfma_gemm<128, 1><<<dim3(32, 12), 256, 0, stream>>>(xb, wib, b_in,
                                                        nullptr, qbf, kbf, vtb,
                                                        time_ids, (const float2*)rtab,
                                                        BB * LL, 3 * DIMD, DIMD);
    attn_mfma<<<256, 512, 0, stream>>>(qbf, kbf, vtb, time_ids,
                                       rel_t, post_t, aob);
    mfma_gemm<64, 0><<<dim3(32, 8), 256, 0, stream>>>(aob, wob, b_out,
                                                      out, nullptr, nullptr, nullptr,
                                                      nullptr, nullptr,
                                                      BB * LL, DIMD, DIMD);
}